// Round 3
// baseline (14.921 us; speedup 1.0000x reference)
//
#include <hip/hip_runtime.h>

// RoiPooling: img [B,32,32,256] f32, rois [B,64,4] f32 (x,y,w,h)
// Out [B*R, 21, 256]; bin order: 0 = level1, 1..4 = level2 (i*2+j),
// 5..20 = level4 (ix*4+jy).
// Level-1/2 boundaries bit-match even level-4 boundaries (k*(h/4) pow2-exact),
// so only the 4x4 level-4 grid is pooled from pixels; coarser levels reduce it.
// jnp.round == round-half-to-even == __float2int_rn.
//
// R2 -> R3: latency-bound at 4 waves/SIMD. Split channels across 2 blocks per
// ROI (grid 512), 2 channels/thread via float2 -> 32 waves/CU (8/SIMD, HW max).

#define IMG_H 32
#define IMG_W 32
#define NCH   256

static __device__ __forceinline__ float2 fmax2(float2 a, float2 b) {
    return make_float2(fmaxf(a.x, b.x), fmaxf(a.y, b.y));
}

__global__ __launch_bounds__(1024) void roi_pool_kernel(
    const float* __restrict__ img,   // [B, H, W, C]
    const float* __restrict__ rois,  // [B*R, 4]
    float* __restrict__ out)         // [B*R, 21, C]
{
    const int bid  = blockIdx.x;
    const int br   = bid & 255;       // b*R + r   (grid = 512)
    const int half = bid >> 8;        // channel half: 0 -> ch 0..127, 1 -> 128..255
    const int b    = br >> 6;         // R = 64
    const int tid  = threadIdx.x;
    const int g    = tid & 63;        // float2 channel group within half
    const int ix   = (tid >> 6) & 3;  // column bin
    const int jy   = tid >> 8;        // row bin
    const int ch   = half * 128 + g * 2;

    const float4 roi = *reinterpret_cast<const float4*>(rois + (size_t)br * 4);
    const float x = roi.x, y = roi.y, w = roi.z, h = roi.w;

    // Column bins from (x, h); row bins from (y, w) — axis swap per reference.
    const float hq = h * 0.25f;   // exact h/4
    const float wq = w * 0.25f;
    const int c0 = max(__float2int_rn(x + (float)ix       * hq), 0);
    const int c1 = min(__float2int_rn(x + (float)(ix + 1) * hq), IMG_W);
    const int r0 = max(__float2int_rn(y + (float)jy       * wq), 0);
    const int r1 = min(__float2int_rn(y + (float)(jy + 1) * wq), IMG_H);

    const float NEG = -__builtin_inff();
    float2 m0 = make_float2(NEG, NEG);
    float2 m1 = m0;

    const float* basep = img + (size_t)b * IMG_H * IMG_W * NCH + ch;
    for (int row = r0; row < r1; ++row) {
        const float* rp = basep + (size_t)row * (IMG_W * NCH);
        int col = c0;
        // two rotating accumulators -> >=2 independent loads in flight
        for (; col + 2 <= c1; col += 2) {
            const float2 v0 = *reinterpret_cast<const float2*>(rp + (size_t)col       * NCH);
            const float2 v1 = *reinterpret_cast<const float2*>(rp + (size_t)(col + 1) * NCH);
            m0 = fmax2(m0, v0);
            m1 = fmax2(m1, v1);
        }
        if (col < c1) {
            m0 = fmax2(m0, *reinterpret_cast<const float2*>(rp + (size_t)col * NCH));
        }
    }
    const float2 m = fmax2(m0, m1);

    float* ob = out + (size_t)br * 21 * NCH;

    // level 4: bin 5 + ix*4 + jy
    *reinterpret_cast<float2*>(ob + (size_t)(5 + ix * 4 + jy) * NCH + ch) = m;

    // share the 4x4 grid for level-2 / level-1 reduction
    __shared__ float2 P[4][4][64];   // [ix][jy][g], 8 KB
    P[ix][jy][g] = m;
    __syncthreads();

    if (tid < 256) {
        // level 2: 4 bins x 64 groups. bin (i,j) = max of level4 (2i..2i+1, 2j..2j+1)
        const int gg = tid & 63;
        const int bb = tid >> 6;      // 0..3
        const int i  = bb >> 1, j = bb & 1;
        const float2 v = fmax2(
            fmax2(P[2 * i][2 * j][gg],     P[2 * i][2 * j + 1][gg]),
            fmax2(P[2 * i + 1][2 * j][gg], P[2 * i + 1][2 * j + 1][gg]));
        *reinterpret_cast<float2*>(ob + (size_t)(1 + i * 2 + j) * NCH + half * 128 + gg * 2) = v;
    } else if (tid < 320) {
        // level 1: max over all 16 level-4 bins
        const int gg = tid & 63;
        float2 v = P[0][0][gg];
#pragma unroll
        for (int i = 0; i < 4; ++i)
#pragma unroll
            for (int j = 0; j < 4; ++j)
                if (i | j) v = fmax2(v, P[i][j][gg]);
        *reinterpret_cast<float2*>(ob + (size_t)(half * 128 + gg * 2)) = v;
    }
}

extern "C" void kernel_launch(void* const* d_in, const int* in_sizes, int n_in,
                              void* d_out, int out_size, void* d_ws, size_t ws_size,
                              hipStream_t stream) {
    const float* img  = (const float*)d_in[0];
    const float* rois = (const float*)d_in[1];
    float* out = (float*)d_out;

    const int n_rois = in_sizes[1] / 4;   // B * R = 256
    roi_pool_kernel<<<n_rois * 2, 1024, 0, stream>>>(img, rois, out);
}

// Round 4
// 11.407 us; speedup vs baseline: 1.3081x; 1.3081x over previous
//
#include <hip/hip_runtime.h>

// RoiPooling: img [B,32,32,256] f32, rois [B,64,4] f32 (x,y,w,h)
// Out [B*R, 21, 256]; bin order: 0 = level1, 1..4 = level2 (i*2+j),
// 5..20 = level4 (ix*4+jy).
// Level-1/2 boundaries bit-match even level-4 boundaries (k*(h/4) pow2-exact),
// so only the 4x4 level-4 grid is pooled from pixels; coarser levels reduce it.
// jnp.round == round-half-to-even == __float2int_rn.
//
// R3 post-mortem: more waves (float2 split) REGRESSED -> not TLP-bound; the
// per-thread dependent L2-load chain is the bottleneck. R4: bin spans are
// provably <= 5 (round(a+d)-round(a) <= d+1, d = h/4 < 5), so fully unroll a
// 5x5 predicated load block with clamped addresses (duplicates = L1 hits) ->
// all 25 float4 loads independent and in flight at once; one L2 round trip
// instead of ~12 serialized ones.

#define IMG_H 32
#define IMG_W 32
#define NCH   256
#define SPAN  5

static __device__ __forceinline__ float4 fmax4(float4 a, float4 b) {
    return make_float4(fmaxf(a.x, b.x), fmaxf(a.y, b.y),
                       fmaxf(a.z, b.z), fmaxf(a.w, b.w));
}

__global__ __launch_bounds__(1024) void roi_pool_kernel(
    const float* __restrict__ img,   // [B, H, W, C]
    const float* __restrict__ rois,  // [B*R, 4]
    float* __restrict__ out)         // [B*R, 21, C]
{
    const int br  = blockIdx.x;       // b*R + r
    const int b   = br >> 6;          // R = 64
    const int tid = threadIdx.x;
    const int c4  = tid & 63;         // float4 channel group: channels 4*c4..4*c4+3
    const int ix  = (tid >> 6) & 3;   // column bin
    const int jy  = tid >> 8;         // row bin

    const float4 roi = *reinterpret_cast<const float4*>(rois + (size_t)br * 4);
    const float x = roi.x, y = roi.y, w = roi.z, h = roi.w;

    // Column bins from (x, h); row bins from (y, w) — axis swap per reference.
    const float hq = h * 0.25f;   // exact h/4
    const float wq = w * 0.25f;
    const int c0 = max(__float2int_rn(x + (float)ix       * hq), 0);
    const int c1 = min(__float2int_rn(x + (float)(ix + 1) * hq), IMG_W);
    const int r0 = max(__float2int_rn(y + (float)jy       * wq), 0);
    const int r1 = min(__float2int_rn(y + (float)(jy + 1) * wq), IMG_H);

    const float* basep = img + (size_t)b * IMG_H * IMG_W * NCH + (size_t)c4 * 4;

    // Phase 1: issue all SPANxSPAN loads, fully independent (clamped addrs).
    float4 v[SPAN * SPAN];
#pragma unroll
    for (int j = 0; j < SPAN; ++j) {
        const int row = min(r0 + j, r1 - 1);
        const float* rp = basep + (size_t)row * (IMG_W * NCH);
#pragma unroll
        for (int k = 0; k < SPAN; ++k) {
            const int col = min(c0 + k, c1 - 1);
            v[j * SPAN + k] = *reinterpret_cast<const float4*>(rp + (size_t)col * NCH);
        }
    }

    // Phase 2: predicated max-reduce.
    const float NEG = -__builtin_inff();
    float4 m = make_float4(NEG, NEG, NEG, NEG);
#pragma unroll
    for (int j = 0; j < SPAN; ++j) {
        const bool rok = (r0 + j) < r1;
#pragma unroll
        for (int k = 0; k < SPAN; ++k) {
            const bool ok = rok && ((c0 + k) < c1);
            const float4 t = v[j * SPAN + k];
            m = ok ? fmax4(m, t) : m;
        }
    }

    float* ob = out + (size_t)br * 21 * NCH;

    // level 4: bin 5 + ix*4 + jy
    *reinterpret_cast<float4*>(ob + (size_t)(5 + ix * 4 + jy) * NCH + (size_t)c4 * 4) = m;

    // share the 4x4 grid for level-2 / level-1 reduction
    __shared__ float4 P[4][4][64];   // [ix][jy][c4], 16 KB
    P[ix][jy][c4] = m;
    __syncthreads();

    if (tid < 256) {
        // level 2: 4 bins x 64 c4-groups. bin (i,j) = max of level4 (2i..2i+1, 2j..2j+1)
        const int cc = tid & 63;
        const int bb = tid >> 6;      // 0..3
        const int i  = bb >> 1, j = bb & 1;
        const float4 q = fmax4(
            fmax4(P[2 * i][2 * j][cc],     P[2 * i][2 * j + 1][cc]),
            fmax4(P[2 * i + 1][2 * j][cc], P[2 * i + 1][2 * j + 1][cc]));
        *reinterpret_cast<float4*>(ob + (size_t)(1 + i * 2 + j) * NCH + (size_t)cc * 4) = q;
    } else if (tid < 320) {
        // level 1: max over all 16 level-4 bins
        const int cc = tid & 63;
        float4 q = P[0][0][cc];
#pragma unroll
        for (int i = 0; i < 4; ++i)
#pragma unroll
            for (int j = 0; j < 4; ++j)
                if (i | j) q = fmax4(q, P[i][j][cc]);
        *reinterpret_cast<float4*>(ob + (size_t)cc * 4) = q;
    }
}

extern "C" void kernel_launch(void* const* d_in, const int* in_sizes, int n_in,
                              void* d_out, int out_size, void* d_ws, size_t ws_size,
                              hipStream_t stream) {
    const float* img  = (const float*)d_in[0];
    const float* rois = (const float*)d_in[1];
    float* out = (float*)d_out;

    const int n_rois = in_sizes[1] / 4;   // B * R = 256
    roi_pool_kernel<<<n_rois, 1024, 0, stream>>>(img, rois, out);
}

// Round 5
// 10.207 us; speedup vs baseline: 1.4619x; 1.1176x over previous
//
#include <hip/hip_runtime.h>

// RoiPooling: img [B,32,32,256] f32, rois [B,64,4] f32 (x,y,w,h)
// Out [B*R, 21, 256]; bin order: 0 = level1, 1..4 = level2 (i*2+j),
// 5..20 = level4 (ix*4+jy).
// Level-1/2 boundaries bit-match even level-4 boundaries (k*(h/4) pow2-exact),
// so only the 4x4 level-4 grid is pooled from pixels; coarser levels reduce it.
// jnp.round == round-half-to-even == __float2int_rn.
//
// R4 -> R5: predication removed. The clamped load address
// (min(r0+j, r1-1), min(c0+k, c1-1)) always lies INSIDE the bin
// [r0,r1)x[c0,c1) (setup guarantees every bin spans >= 2 px, ROIs in-bounds),
// so duplicate loads are members of the max-set and an UNMASKED max over all
// 25 values is bit-identical to the masked max. Saves ~40% of per-thread VALU
// (no cndmask/bool chain). R2~=R4 within 1% suggests we sit on the ~10us
// launch/replay overhead floor; this is the confirmation experiment.

#define IMG_H 32
#define IMG_W 32
#define NCH   256
#define SPAN  5

static __device__ __forceinline__ float4 fmax4(float4 a, float4 b) {
    return make_float4(fmaxf(a.x, b.x), fmaxf(a.y, b.y),
                       fmaxf(a.z, b.z), fmaxf(a.w, b.w));
}

__global__ __launch_bounds__(1024) void roi_pool_kernel(
    const float* __restrict__ img,   // [B, H, W, C]
    const float* __restrict__ rois,  // [B*R, 4]
    float* __restrict__ out)         // [B*R, 21, C]
{
    const int br  = blockIdx.x;       // b*R + r
    const int b   = br >> 6;          // R = 64
    const int tid = threadIdx.x;
    const int c4  = tid & 63;         // float4 channel group: channels 4*c4..4*c4+3
    const int ix  = (tid >> 6) & 3;   // column bin
    const int jy  = tid >> 8;         // row bin

    const float4 roi = *reinterpret_cast<const float4*>(rois + (size_t)br * 4);
    const float x = roi.x, y = roi.y, w = roi.z, h = roi.w;

    // Column bins from (x, h); row bins from (y, w) — axis swap per reference.
    const float hq = h * 0.25f;   // exact h/4
    const float wq = w * 0.25f;
    const int c0 = max(__float2int_rn(x + (float)ix       * hq), 0);
    const int c1 = min(__float2int_rn(x + (float)(ix + 1) * hq), IMG_W);
    const int r0 = max(__float2int_rn(y + (float)jy       * wq), 0);
    const int r1 = min(__float2int_rn(y + (float)(jy + 1) * wq), IMG_H);

    const float* basep = img + (size_t)b * IMG_H * IMG_W * NCH + (size_t)c4 * 4;

    // All SPANxSPAN loads independent; clamped addrs stay inside the bin.
    float4 v[SPAN * SPAN];
#pragma unroll
    for (int j = 0; j < SPAN; ++j) {
        const int row = min(r0 + j, r1 - 1);
        const float* rp = basep + (size_t)row * (IMG_W * NCH);
#pragma unroll
        for (int k = 0; k < SPAN; ++k) {
            const int col = min(c0 + k, c1 - 1);
            v[j * SPAN + k] = *reinterpret_cast<const float4*>(rp + (size_t)col * NCH);
        }
    }

    // Unmasked max over all 25 values (== masked max, see header comment).
    float4 m = v[0];
#pragma unroll
    for (int i = 1; i < SPAN * SPAN; ++i) m = fmax4(m, v[i]);

    float* ob = out + (size_t)br * 21 * NCH;

    // level 4: bin 5 + ix*4 + jy
    *reinterpret_cast<float4*>(ob + (size_t)(5 + ix * 4 + jy) * NCH + (size_t)c4 * 4) = m;

    // share the 4x4 grid for level-2 / level-1 reduction
    __shared__ float4 P[4][4][64];   // [ix][jy][c4], 16 KB
    P[ix][jy][c4] = m;
    __syncthreads();

    if (tid < 256) {
        // level 2: 4 bins x 64 c4-groups. bin (i,j) = max of level4 (2i..2i+1, 2j..2j+1)
        const int cc = tid & 63;
        const int bb = tid >> 6;      // 0..3
        const int i  = bb >> 1, j = bb & 1;
        const float4 q = fmax4(
            fmax4(P[2 * i][2 * j][cc],     P[2 * i][2 * j + 1][cc]),
            fmax4(P[2 * i + 1][2 * j][cc], P[2 * i + 1][2 * j + 1][cc]));
        *reinterpret_cast<float4*>(ob + (size_t)(1 + i * 2 + j) * NCH + (size_t)cc * 4) = q;
    } else if (tid < 320) {
        // level 1: max over all 16 level-4 bins
        const int cc = tid & 63;
        float4 q = P[0][0][cc];
#pragma unroll
        for (int i = 0; i < 4; ++i)
#pragma unroll
            for (int j = 0; j < 4; ++j)
                if (i | j) q = fmax4(q, P[i][j][cc]);
        *reinterpret_cast<float4*>(ob + (size_t)cc * 4) = q;
    }
}

extern "C" void kernel_launch(void* const* d_in, const int* in_sizes, int n_in,
                              void* d_out, int out_size, void* d_ws, size_t ws_size,
                              hipStream_t stream) {
    const float* img  = (const float*)d_in[0];
    const float* rois = (const float*)d_in[1];
    float* out = (float*)d_out;

    const int n_rois = in_sizes[1] / 4;   // B * R = 256
    roi_pool_kernel<<<n_rois, 1024, 0, stream>>>(img, rois, out);
}